// Round 1
// baseline (2125.084 us; speedup 1.0000x reference)
//
#include <hip/hip_runtime.h>
#include <hip/hip_bf16.h>
#include <cstdio>

// Problem constants (from reference): x (4,256,64,64), res (4,128,128,128)
// upsampled xu: (4,256,128,128); tokens = (b,h,w) flattened = 65536; C=256, E=128
// heads=2, head dim e=128, axial seq len T=128, scale = 128^-0.5
//
// Workspace layout (bytes):
//   [0,            33554432)   xu   bf16 [token][256]      (b,h,w,c)
//   [33554432,    134217728)   qkv  bf16 [token][768]      cols 0:256 Q (later O), 256:512 K, 512:768 V
//   [134217728,   167772160)   acc  bf16 [token][256]      ah + aw (pre-ReLU)
//   [167772160,   167773184)   stats f32 [128][2]          (mu, rstd)
// Total ~168 MB.

typedef __hip_bfloat16 bf16;

#define NTOK 65536

// ---------------------------------------------------------------- upsample
// bilinear 2x align_corners: in 64x64 -> out 128x128, scale 63/127
__global__ __launch_bounds__(256) void k_upsample(const float* __restrict__ x,
                                                  bf16* __restrict__ xu) {
  const int bh = blockIdx.x;            // 0..511 = b*128 + h
  const int b  = bh >> 7, h = bh & 127;
  float ch = h * (63.0f / 127.0f);
  int i0 = (int)floorf(ch); if (i0 > 62) i0 = 62;
  const float wh = ch - (float)i0;
  __shared__ float rows[2][32][64];     // [row][c-chunk][win] 16KB
  const int tid = threadIdx.x;
  for (int cc = 0; cc < 256; cc += 32) {
    __syncthreads();
    for (int li = tid; li < 4096; li += 256) {
      int r = li >> 11, c = (li >> 6) & 31, w = li & 63;
      rows[r][c][w] = x[(((size_t)(b * 256 + cc + c) * 64) + (i0 + r)) * 64 + w];
    }
    __syncthreads();
    for (int li = tid; li < 4096; li += 256) {
      int c = li & 31, w = li >> 5;     // w 0..127
      float cw = w * (63.0f / 127.0f);
      int j0 = (int)floorf(cw); if (j0 > 62) j0 = 62;
      float ww = cw - (float)j0;
      float v0 = rows[0][c][j0] * (1.f - ww) + rows[0][c][j0 + 1] * ww;
      float v1 = rows[1][c][j0] * (1.f - ww) + rows[1][c][j0 + 1] * ww;
      float v  = v0 * (1.f - wh) + v1 * wh;
      int token = (bh << 7) + w;
      xu[(size_t)token * 256 + cc + c] = __float2bfloat16(v);
    }
  }
}

// ---------------------------------------------------------------- QKV GEMM
// out[token][768] = xu[token][0:256] @ [wq | wkv]; M=65536 K=256 N=768
__global__ __launch_bounds__(256) void k_qkv(const bf16* __restrict__ A,
                                             const float* __restrict__ wq,
                                             const float* __restrict__ wkv,
                                             bf16* __restrict__ out) {
  __shared__ float As[64][33];
  __shared__ float Bs[32][65];
  const int tid = threadIdx.x;
  const int tx = tid & 15, ty = tid >> 4;
  const int m0 = blockIdx.x * 64;
  const int n0 = blockIdx.y * 64;
  const float* Bsrc; int ldb, ncol;
  if (n0 < 256) { Bsrc = wq;  ldb = 256; ncol = n0; }
  else          { Bsrc = wkv; ldb = 512; ncol = n0 - 256; }
  const int arow = tid >> 2, ac0 = (tid & 3) * 8;
  const int brow = tid >> 3, bc0 = (tid & 7) * 8;
  float acc[4][4] = {};
  for (int k0 = 0; k0 < 256; k0 += 32) {
    const bf16* ap = A + (size_t)(m0 + arow) * 256 + k0 + ac0;
#pragma unroll
    for (int u = 0; u < 8; u++) As[arow][ac0 + u] = __bfloat162float(ap[u]);
    const float* bp = Bsrc + (size_t)(k0 + brow) * ldb + ncol + bc0;
#pragma unroll
    for (int u = 0; u < 8; u++) Bs[brow][bc0 + u] = bp[u];
    __syncthreads();
#pragma unroll
    for (int kk = 0; kk < 32; kk++) {
      float a[4], bb[4];
#pragma unroll
      for (int i = 0; i < 4; i++) a[i] = As[ty * 4 + i][kk];
#pragma unroll
      for (int j = 0; j < 4; j++) bb[j] = Bs[kk][tx * 4 + j];
#pragma unroll
      for (int i = 0; i < 4; i++)
#pragma unroll
        for (int j = 0; j < 4; j++) acc[i][j] += a[i] * bb[j];
    }
    __syncthreads();
  }
#pragma unroll
  for (int i = 0; i < 4; i++) {
    bf16* op = out + (size_t)(m0 + ty * 4 + i) * 768 + n0 + tx * 4;
#pragma unroll
    for (int j = 0; j < 4; j++) op[j] = __float2bfloat16(acc[i][j]);
  }
}

// ---------------------------------------------------------------- attention
// one block per (seq, head); seq = b*128 + pos; T=128, e=128
// dir 0 (H): token(t) = b*16384 + t*128 + pos  (pos = w)
// dir 1 (W): token(t) = b*16384 + pos*128 + t  (pos = h)
// O overwrites the Q slice of this block's tokens.
__global__ __launch_bounds__(256) void k_attn(bf16* __restrict__ qkv, int dir) {
  const int bid  = blockIdx.x;
  const int head = bid & 1;
  const int s    = bid >> 1;
  const int b    = s >> 7;
  const int pos  = s & 127;
  const int base   = b * 16384 + (dir == 0 ? pos : pos * 128);
  const int stride = (dir == 0 ? 128 : 1);
  const int tid = threadIdx.x;
  const int tx = tid & 15, ty = tid >> 4;

  __shared__ bf16 Qs[128][17];
  __shared__ bf16 Ks[128][17];
  __shared__ bf16 Vs[16][128];
  __shared__ bf16 Ps[128][129];

  float acc[8][8] = {};
  // Phase A: S = Q K^T  (tile 128x128, BK=16 over e)
  {
    const int row = tid >> 1, col0 = (tid & 1) * 8;
    for (int e0 = 0; e0 < 128; e0 += 16) {
      const bf16* qp = qkv + (size_t)(base + row * stride) * 768 + head * 128 + e0 + col0;
      const bf16* kp = qkv + (size_t)(base + row * stride) * 768 + 256 + head * 128 + e0 + col0;
#pragma unroll
      for (int u = 0; u < 8; u++) { Qs[row][col0 + u] = qp[u]; Ks[row][col0 + u] = kp[u]; }
      __syncthreads();
#pragma unroll
      for (int kk = 0; kk < 16; kk++) {
        float a[8], bb[8];
#pragma unroll
        for (int i = 0; i < 8; i++) a[i] = __bfloat162float(Qs[ty * 8 + i][kk]);
#pragma unroll
        for (int j = 0; j < 8; j++) bb[j] = __bfloat162float(Ks[tx * 8 + j][kk]);
#pragma unroll
        for (int i = 0; i < 8; i++)
#pragma unroll
          for (int j = 0; j < 8; j++) acc[i][j] += a[i] * bb[j];
      }
      __syncthreads();
    }
  }
  // Phase B: row softmax (row = ty*8+i spans the 16 tx lanes)
  const float scale = 0.0883883476483184f;  // 128^-0.5
#pragma unroll
  for (int i = 0; i < 8; i++) {
    float m = -3e38f;
#pragma unroll
    for (int j = 0; j < 8; j++) { acc[i][j] *= scale; m = fmaxf(m, acc[i][j]); }
#pragma unroll
    for (int d = 1; d < 16; d <<= 1) m = fmaxf(m, __shfl_xor(m, d));
    float sum = 0.f;
#pragma unroll
    for (int j = 0; j < 8; j++) { acc[i][j] = __expf(acc[i][j] - m); sum += acc[i][j]; }
#pragma unroll
    for (int d = 1; d < 16; d <<= 1) sum += __shfl_xor(sum, d);
    float inv = 1.f / sum;
#pragma unroll
    for (int j = 0; j < 8; j++) Ps[ty * 8 + i][tx * 8 + j] = __float2bfloat16(acc[i][j] * inv);
  }
  __syncthreads();
  // Phase C: O = P @ V  (BK=16 over j)
#pragma unroll
  for (int i = 0; i < 8; i++)
#pragma unroll
    for (int j = 0; j < 8; j++) acc[i][j] = 0.f;
  {
    const int vrow = tid >> 4, vcol = (tid & 15) * 8;
    for (int j0 = 0; j0 < 128; j0 += 16) {
      const bf16* vp = qkv + (size_t)(base + (j0 + vrow) * stride) * 768 + 512 + head * 128 + vcol;
#pragma unroll
      for (int u = 0; u < 8; u++) Vs[vrow][vcol + u] = vp[u];
      __syncthreads();
#pragma unroll
      for (int kk = 0; kk < 16; kk++) {
        float a[8], bb[8];
#pragma unroll
        for (int i = 0; i < 8; i++) a[i] = __bfloat162float(Ps[ty * 8 + i][j0 + kk]);
#pragma unroll
        for (int j = 0; j < 8; j++) bb[j] = __bfloat162float(Vs[kk][tx * 8 + j]);
#pragma unroll
        for (int i = 0; i < 8; i++)
#pragma unroll
          for (int j = 0; j < 8; j++) acc[i][j] += a[i] * bb[j];
      }
      __syncthreads();
    }
  }
  // write O over Q slice (own tokens, own head columns -> race-free)
#pragma unroll
  for (int i = 0; i < 8; i++) {
    bf16* op = qkv + (size_t)(base + (ty * 8 + i) * stride) * 768 + head * 128;
#pragma unroll
    for (int j = 0; j < 8; j++) op[tx * 8 + j] = __float2bfloat16(acc[i][j]);
  }
}

// ---------------------------------------------------------------- out-proj
// acc[token][256] (+)= O[token][0:256] @ wo + wob ; O lives in qkv cols 0:256
__global__ __launch_bounds__(256) void k_proj(const bf16* __restrict__ O,
                                              const float* __restrict__ wo,
                                              const float* __restrict__ wob,
                                              bf16* __restrict__ accb, int add) {
  __shared__ float As[64][33];
  __shared__ float Bs[32][65];
  const int tid = threadIdx.x;
  const int tx = tid & 15, ty = tid >> 4;
  const int m0 = blockIdx.x * 64;
  const int n0 = blockIdx.y * 64;
  const int arow = tid >> 2, ac0 = (tid & 3) * 8;
  const int brow = tid >> 3, bc0 = (tid & 7) * 8;
  float acc[4][4] = {};
  for (int k0 = 0; k0 < 256; k0 += 32) {
    const bf16* ap = O + (size_t)(m0 + arow) * 768 + k0 + ac0;
#pragma unroll
    for (int u = 0; u < 8; u++) As[arow][ac0 + u] = __bfloat162float(ap[u]);
    const float* bp = wo + (size_t)(k0 + brow) * 256 + n0 + bc0;
#pragma unroll
    for (int u = 0; u < 8; u++) Bs[brow][bc0 + u] = bp[u];
    __syncthreads();
#pragma unroll
    for (int kk = 0; kk < 32; kk++) {
      float a[4], bb[4];
#pragma unroll
      for (int i = 0; i < 4; i++) a[i] = As[ty * 4 + i][kk];
#pragma unroll
      for (int j = 0; j < 4; j++) bb[j] = Bs[kk][tx * 4 + j];
#pragma unroll
      for (int i = 0; i < 4; i++)
#pragma unroll
        for (int j = 0; j < 4; j++) acc[i][j] += a[i] * bb[j];
    }
    __syncthreads();
  }
#pragma unroll
  for (int i = 0; i < 4; i++) {
#pragma unroll
    for (int j = 0; j < 4; j++) {
      int n = n0 + tx * 4 + j;
      float v = acc[i][j] + wob[n];
      size_t oi = (size_t)(m0 + ty * 4 + i) * 256 + n;
      if (add) v += __bfloat162float(accb[oi]);
      accb[oi] = __float2bfloat16(v);
    }
  }
}

// ---------------------------------------------------------------- conv1x1
// y[b,e,h,w] = relu( [relu(acc) | xu | res][token][0:640] @ conv_w )
__global__ __launch_bounds__(256) void k_conv(const bf16* __restrict__ accb,
                                              const bf16* __restrict__ xu,
                                              const float* __restrict__ res,
                                              const float* __restrict__ cw,
                                              float* __restrict__ y) {
  __shared__ float As[64][33];
  __shared__ float Bs[32][65];
  const int tid = threadIdx.x;
  const int tx = tid & 15, ty = tid >> 4;
  const int m0 = blockIdx.x * 64;
  const int n0 = blockIdx.y * 64;
  const int arow = tid >> 2, ac0 = (tid & 3) * 8;
  const int krow = tid >> 3, mc0 = (tid & 7) * 8;
  const int brow = tid >> 3, bc0 = (tid & 7) * 8;
  const int bb_ = m0 >> 14, hh = (m0 >> 7) & 127, w0 = m0 & 127;
  float acc[4][4] = {};
  for (int k0 = 0; k0 < 640; k0 += 32) {
    if (k0 < 256) {
      const bf16* ap = accb + (size_t)(m0 + arow) * 256 + k0 + ac0;
#pragma unroll
      for (int u = 0; u < 8; u++) As[arow][ac0 + u] = fmaxf(__bfloat162float(ap[u]), 0.f);
    } else if (k0 < 512) {
      const bf16* ap = xu + (size_t)(m0 + arow) * 256 + (k0 - 256) + ac0;
#pragma unroll
      for (int u = 0; u < 8; u++) As[arow][ac0 + u] = __bfloat162float(ap[u]);
    } else {
      const float* rp = res + (((size_t)(bb_ * 128 + (k0 - 512 + krow)) * 128 + hh) * 128) + w0 + mc0;
#pragma unroll
      for (int u = 0; u < 8; u++) As[mc0 + u][krow] = rp[u];
    }
    const float* bp = cw + (size_t)(k0 + brow) * 128 + n0 + bc0;
#pragma unroll
    for (int u = 0; u < 8; u++) Bs[brow][bc0 + u] = bp[u];
    __syncthreads();
#pragma unroll
    for (int kk = 0; kk < 32; kk++) {
      float a[4], bb[4];
#pragma unroll
      for (int i = 0; i < 4; i++) a[i] = As[ty * 4 + i][kk];
#pragma unroll
      for (int j = 0; j < 4; j++) bb[j] = Bs[kk][tx * 4 + j];
#pragma unroll
      for (int i = 0; i < 4; i++)
#pragma unroll
        for (int j = 0; j < 4; j++) acc[i][j] += a[i] * bb[j];
    }
    __syncthreads();
  }
#pragma unroll
  for (int i = 0; i < 4; i++) {
    int token = m0 + ty * 4 + i;
    int b2 = token >> 14, hw = token & 16383;
#pragma unroll
    for (int j = 0; j < 4; j++) {
      int n = n0 + tx * 4 + j;
      y[((size_t)(b2 * 128 + n) << 14) + hw] = fmaxf(acc[i][j], 0.f);
    }
  }
}

// ---------------------------------------------------------------- BN stats
__global__ __launch_bounds__(256) void k_bnstats(const float* __restrict__ y,
                                                 float* __restrict__ stats) {
  const int e = blockIdx.x;  // channel
  const int tid = threadIdx.x;
  float s = 0.f, s2 = 0.f;
  for (int i = tid; i < 65536; i += 256) {
    int b = i >> 14, hw = i & 16383;
    float v = y[((size_t)(b * 128 + e) << 14) + hw];
    s += v; s2 += v * v;
  }
  __shared__ float rs[256], rs2[256];
  rs[tid] = s; rs2[tid] = s2;
  __syncthreads();
  for (int d = 128; d > 0; d >>= 1) {
    if (tid < d) { rs[tid] += rs[tid + d]; rs2[tid] += rs2[tid + d]; }
    __syncthreads();
  }
  if (tid == 0) {
    float mu  = rs[0] / 65536.f;
    float var = rs2[0] / 65536.f - mu * mu;  // biased variance
    stats[e * 2]     = mu;
    stats[e * 2 + 1] = rsqrtf(var + 1e-5f);
  }
}

__global__ __launch_bounds__(256) void k_bnapply(float* __restrict__ y,
                                                 const float* __restrict__ stats,
                                                 const float* __restrict__ gamma,
                                                 const float* __restrict__ beta) {
  size_t i = (size_t)blockIdx.x * 256 + threadIdx.x;  // 8388608 elems
  int e = (int)((i >> 14) & 127);
  float mu = stats[e * 2], rstd = stats[e * 2 + 1];
  y[i] = (y[i] - mu) * rstd * gamma[e] + beta[e];
}

// ---------------------------------------------------------------- launcher
extern "C" void kernel_launch(void* const* d_in, const int* in_sizes, int n_in,
                              void* d_out, int out_size, void* d_ws, size_t ws_size,
                              hipStream_t stream) {
  const float* x      = (const float*)d_in[0];
  const float* res    = (const float*)d_in[1];
  const float* wq_h   = (const float*)d_in[2];
  const float* wkv_h  = (const float*)d_in[3];
  const float* wo_h   = (const float*)d_in[4];
  const float* wob_h  = (const float*)d_in[5];
  const float* wq_w   = (const float*)d_in[6];
  const float* wkv_w  = (const float*)d_in[7];
  const float* wo_w   = (const float*)d_in[8];
  const float* wob_w  = (const float*)d_in[9];
  const float* conv_w = (const float*)d_in[10];
  const float* gamma  = (const float*)d_in[11];
  const float* beta   = (const float*)d_in[12];
  float* out = (float*)d_out;

  char* ws = (char*)d_ws;
  bf16*  xu    = (bf16*)ws;
  bf16*  qkv   = (bf16*)(ws + 33554432);
  bf16*  accb  = (bf16*)(ws + 134217728);
  float* stats = (float*)(ws + 167772160);
  if (ws_size < 167772160ull + 1024ull) {
    fprintf(stderr, "kernel_launch: ws_size %zu too small (need %llu)\n",
            ws_size, 167772160ull + 1024ull);
  }

  k_upsample<<<512, 256, 0, stream>>>(x, xu);

  // direction H (axial over rows, seq = (b,w))
  k_qkv <<<dim3(1024, 12), 256, 0, stream>>>(xu, wq_h, wkv_h, qkv);
  k_attn<<<1024, 256, 0, stream>>>(qkv, 0);
  k_proj<<<dim3(1024, 4), 256, 0, stream>>>(qkv, wo_h, wob_h, accb, 0);

  // direction W (axial over cols, seq = (b,h))
  k_qkv <<<dim3(1024, 12), 256, 0, stream>>>(xu, wq_w, wkv_w, qkv);
  k_attn<<<1024, 256, 0, stream>>>(qkv, 1);
  k_proj<<<dim3(1024, 4), 256, 0, stream>>>(qkv, wo_w, wob_w, accb, 1);

  // concat -> conv1x1 -> relu -> (y in d_out) -> BN
  k_conv<<<dim3(1024, 2), 256, 0, stream>>>(accb, xu, res, conv_w, out);
  k_bnstats<<<128, 256, 0, stream>>>(out, stats);
  k_bnapply<<<32768, 256, 0, stream>>>(out, stats, gamma, beta);
}

// Round 2
// 587.904 us; speedup vs baseline: 3.6147x; 3.6147x over previous
//
#include <hip/hip_runtime.h>
#include <hip/hip_bf16.h>
#include <cstdio>

// BlockAxialUp on MI355X, round 2: full MFMA rewrite.
// x (4,256,64,64) -> upsample2x -> xu (tokens=65536, C=256) bf16
// dir H/W: qkv gemm -> axial attn (2 heads, e=128, T=128) -> proj (sum in d_out as bf16)
// concat[relu(acc)|xu|res] @ conv_w -> relu -> ytmp -> BN (2-pass) -> d_out f32
//
// ws layout (bytes):
//   0        wqkvT_h bf16 [768][256]   (rows: q 0:256, k 256:512, v 512:768)
//   393216   wqkvT_w
//   786432   woT_h  bf16 [256][256]
//   917504   woT_w
//   1048576  convT  bf16 [128][640]
//   1245184  xu     bf16 [65536][256]
//   34799616 Q plane bf16 [65536][256]   (O written in-place; later ytmp f32 [65536][128])
//   68354048 K plane                     (later partial f32 [128][128][2] + stats)
//   101908480 V plane                    -> end 135462912 (~129 MB)
// accb (ah+aw, bf16 [65536][256]) lives in d_out; final f32 output overwrites it.

typedef short bf16x8 __attribute__((ext_vector_type(8)));
typedef float f32x4 __attribute__((ext_vector_type(4)));

#define MFMA16(a, b, c) __builtin_amdgcn_mfma_f32_16x16x32_bf16((a), (b), (c), 0, 0, 0)

__device__ __forceinline__ short f2bf(float v) {
  __hip_bfloat16 h = __float2bfloat16(v);
  union { __hip_bfloat16 h; short s; } u; u.h = h; return u.s;
}
__device__ __forceinline__ float bf2f(short s) {
  return __uint_as_float(((unsigned int)(unsigned short)s) << 16);
}

// ---------------- weight prep: dst[n][k] = bf16(src[k][n]) ----------------
__global__ __launch_bounds__(256) void k_wt(const float* __restrict__ src,
                                            int K, int N, short* __restrict__ dst) {
  __shared__ float tile[32][33];
  const int k0 = blockIdx.x * 32, n0 = blockIdx.y * 32;
  const int tx = threadIdx.x & 31, ty = threadIdx.x >> 5;
#pragma unroll
  for (int i = 0; i < 4; i++)
    tile[ty + i * 8][tx] = src[(size_t)(k0 + ty + i * 8) * N + n0 + tx];
  __syncthreads();
#pragma unroll
  for (int i = 0; i < 4; i++)
    dst[(size_t)(n0 + ty + i * 8) * K + k0 + tx] = f2bf(tile[tx][ty + i * 8]);
}

// ---------------- upsample 2x bilinear align_corners ----------------
__global__ __launch_bounds__(256) void k_upsample(const float* __restrict__ x,
                                                  short* __restrict__ xu) {
  const int bh = blockIdx.x;            // b*128 + h_out
  const int b  = bh >> 7, h = bh & 127;
  float ch = h * (63.0f / 127.0f);
  int i0 = (int)floorf(ch); if (i0 > 62) i0 = 62;
  const float wh = ch - (float)i0;
  __shared__ float rows[2][32][64];
  const int tid = threadIdx.x;
  for (int cc = 0; cc < 256; cc += 32) {
    __syncthreads();
    for (int li = tid; li < 4096; li += 256) {
      int r = li >> 11, c = (li >> 6) & 31, w = li & 63;
      rows[r][c][w] = x[(((size_t)(b * 256 + cc + c) * 64) + (i0 + r)) * 64 + w];
    }
    __syncthreads();
    for (int li = tid; li < 4096; li += 256) {
      int c = li & 31, w = li >> 5;
      float cw = w * (63.0f / 127.0f);
      int j0 = (int)floorf(cw); if (j0 > 62) j0 = 62;
      float ww = cw - (float)j0;
      float v0 = rows[0][c][j0] * (1.f - ww) + rows[0][c][j0 + 1] * ww;
      float v1 = rows[1][c][j0] * (1.f - ww) + rows[1][c][j0 + 1] * ww;
      float v  = v0 * (1.f - wh) + v1 * wh;
      int token = (bh << 7) + w;
      xu[(size_t)token * 256 + cc + c] = f2bf(v);
    }
  }
}

// ---------------- QKV GEMM: [65536,256] @ Bt[768,256]^T -> planes ----------
__global__ __launch_bounds__(256) void k_gemm_qkv(const short* __restrict__ A,
                                                  const short* __restrict__ Bt,
                                                  short* __restrict__ QKV) {
  const int tid = threadIdx.x;
  const int lane = tid & 63, wid = tid >> 6;
  const int lr = lane & 15, kb = lane >> 4;
  const int wr = wid >> 1, wc = wid & 1;
  const int m0 = blockIdx.y * 128, n0 = blockIdx.x * 128;
  f32x4 acc[4][4];
#pragma unroll
  for (int i = 0; i < 4; i++)
#pragma unroll
    for (int j = 0; j < 4; j++) acc[i][j] = (f32x4){0.f, 0.f, 0.f, 0.f};
  const short* arow = A + (size_t)(m0 + wr * 64 + lr) * 256 + kb * 8;
  const short* brow = Bt + (size_t)(n0 + wc * 64 + lr) * 256 + kb * 8;
#pragma unroll
  for (int ks = 0; ks < 8; ks++) {
    bf16x8 a[4], b[4];
#pragma unroll
    for (int mi = 0; mi < 4; mi++)
      a[mi] = *(const bf16x8*)(arow + (size_t)mi * 16 * 256 + ks * 32);
#pragma unroll
    for (int nj = 0; nj < 4; nj++)
      b[nj] = *(const bf16x8*)(brow + (size_t)nj * 16 * 256 + ks * 32);
#pragma unroll
    for (int mi = 0; mi < 4; mi++)
#pragma unroll
      for (int nj = 0; nj < 4; nj++)
        acc[mi][nj] = MFMA16(a[mi], b[nj], acc[mi][nj]);
  }
  short* outp = QKV + (size_t)(n0 >> 8) * 16777216;
  const int colb = (n0 & 255) + wc * 64;
#pragma unroll
  for (int mi = 0; mi < 4; mi++) {
    const int rbase = m0 + wr * 64 + mi * 16 + kb * 4;
#pragma unroll
    for (int nj = 0; nj < 4; nj++) {
      const int c = colb + nj * 16 + lr;
#pragma unroll
      for (int r = 0; r < 4; r++)
        outp[(size_t)(rbase + r) * 256 + c] = f2bf(acc[mi][nj][r]);
    }
  }
}

// ---------------- axial attention (one block = one (seq, head)) ------------
__global__ __launch_bounds__(256) void k_attn(short* __restrict__ Q,
                                              const short* __restrict__ Kp,
                                              const short* __restrict__ Vp,
                                              int dir) {
  __shared__ __align__(16) short Ps[128][136];
  __shared__ __align__(16) short Vt[128][40];
  const int bid = blockIdx.x;
  const int head = bid & 1, s = bid >> 1;
  const int b = s >> 7, pos = s & 127;
  const int tok0 = b * 16384 + (dir ? pos * 128 : pos);
  const int tstep = dir ? 1 : 128;
  const int cb = head * 128;
  const int tid = threadIdx.x;
  const int lane = tid & 63, wid = tid >> 6;
  const int lr = lane & 15, kb = lane >> 4;

  f32x4 acc[2][8];
#pragma unroll
  for (int i = 0; i < 2; i++)
#pragma unroll
    for (int j = 0; j < 8; j++) acc[i][j] = (f32x4){0.f, 0.f, 0.f, 0.f};

  // phase A: S = Q K^T  (rows wid*32..+31, cols 0..127)
#pragma unroll
  for (int es = 0; es < 4; es++) {
    const int e0 = es * 32 + kb * 8;
    bf16x8 aq[2], bk[8];
#pragma unroll
    for (int mi = 0; mi < 2; mi++)
      aq[mi] = *(const bf16x8*)(Q + (size_t)(tok0 + (wid * 32 + mi * 16 + lr) * tstep) * 256 + cb + e0);
#pragma unroll
    for (int nj = 0; nj < 8; nj++)
      bk[nj] = *(const bf16x8*)(Kp + (size_t)(tok0 + (nj * 16 + lr) * tstep) * 256 + cb + e0);
#pragma unroll
    for (int mi = 0; mi < 2; mi++)
#pragma unroll
      for (int nj = 0; nj < 8; nj++)
        acc[mi][nj] = MFMA16(aq[mi], bk[nj], acc[mi][nj]);
  }

  // softmax over cols (row = wid*32 + mi*16 + kb*4 + r, owned by 16-lane group)
  const float scale = 0.08838834764831845f;   // 128^-0.5
#pragma unroll
  for (int mi = 0; mi < 2; mi++) {
#pragma unroll
    for (int r = 0; r < 4; r++) {
      float m = acc[mi][0][r];
#pragma unroll
      for (int nj = 1; nj < 8; nj++) m = fmaxf(m, acc[mi][nj][r]);
      m = fmaxf(m, __shfl_xor(m, 1)); m = fmaxf(m, __shfl_xor(m, 2));
      m = fmaxf(m, __shfl_xor(m, 4)); m = fmaxf(m, __shfl_xor(m, 8));
      float p[8], sum = 0.f;
#pragma unroll
      for (int nj = 0; nj < 8; nj++) { p[nj] = __expf((acc[mi][nj][r] - m) * scale); sum += p[nj]; }
      sum += __shfl_xor(sum, 1); sum += __shfl_xor(sum, 2);
      sum += __shfl_xor(sum, 4); sum += __shfl_xor(sum, 8);
      const float inv = 1.f / sum;
      const int prow = wid * 32 + mi * 16 + kb * 4 + r;
#pragma unroll
      for (int nj = 0; nj < 8; nj++) Ps[prow][nj * 16 + lr] = f2bf(p[nj] * inv);
    }
  }

  // phase C: O = P V  (reuse acc)
#pragma unroll
  for (int i = 0; i < 2; i++)
#pragma unroll
    for (int j = 0; j < 8; j++) acc[i][j] = (f32x4){0.f, 0.f, 0.f, 0.f};

  const int tt2 = tid & 15, eb = (tid >> 4) * 8;
  for (int j0 = 0; j0 < 4; j0++) {
    const int j = j0 * 32;
    const int t0 = j + 2 * tt2;
    bf16x8 v0 = *(const bf16x8*)(Vp + (size_t)(tok0 + t0 * tstep) * 256 + cb + eb);
    bf16x8 v1 = *(const bf16x8*)(Vp + (size_t)(tok0 + (t0 + 1) * tstep) * 256 + cb + eb);
    __syncthreads();   // previous iteration's Vt reads are done
#pragma unroll
    for (int i = 0; i < 8; i++)
      *(unsigned int*)&Vt[eb + i][2 * tt2] =
          (unsigned int)(unsigned short)v0[i] | ((unsigned int)(unsigned short)v1[i] << 16);
    __syncthreads();
    bf16x8 ap[2], bv[8];
#pragma unroll
    for (int mi = 0; mi < 2; mi++)
      ap[mi] = *(const bf16x8*)(&Ps[wid * 32 + mi * 16 + lr][j + kb * 8]);
#pragma unroll
    for (int nj = 0; nj < 8; nj++)
      bv[nj] = *(const bf16x8*)(&Vt[nj * 16 + lr][kb * 8]);
#pragma unroll
    for (int mi = 0; mi < 2; mi++)
#pragma unroll
      for (int nj = 0; nj < 8; nj++)
        acc[mi][nj] = MFMA16(ap[mi], bv[nj], acc[mi][nj]);
  }

  // write O over Q (own rows, own head cols -> race-free)
#pragma unroll
  for (int mi = 0; mi < 2; mi++) {
    const int rbase = wid * 32 + mi * 16 + kb * 4;
#pragma unroll
    for (int nj = 0; nj < 8; nj++) {
      const int c = cb + nj * 16 + lr;
#pragma unroll
      for (int r = 0; r < 4; r++)
        Q[(size_t)(tok0 + (rbase + r) * tstep) * 256 + c] = f2bf(acc[mi][nj][r]);
    }
  }
}

// ---------------- out-proj: accb (+)= O @ woT^T + bias ----------------
__global__ __launch_bounds__(256) void k_gemm_proj(const short* __restrict__ O,
                                                   const short* __restrict__ Bt,
                                                   const float* __restrict__ bias,
                                                   short* __restrict__ accb, int add) {
  const int tid = threadIdx.x;
  const int lane = tid & 63, wid = tid >> 6;
  const int lr = lane & 15, kb = lane >> 4;
  const int wr = wid >> 1, wc = wid & 1;
  const int m0 = blockIdx.y * 128, n0 = blockIdx.x * 128;
  f32x4 acc[4][4];
#pragma unroll
  for (int i = 0; i < 4; i++)
#pragma unroll
    for (int j = 0; j < 4; j++) acc[i][j] = (f32x4){0.f, 0.f, 0.f, 0.f};
  const short* arow = O + (size_t)(m0 + wr * 64 + lr) * 256 + kb * 8;
  const short* brow = Bt + (size_t)(n0 + wc * 64 + lr) * 256 + kb * 8;
#pragma unroll
  for (int ks = 0; ks < 8; ks++) {
    bf16x8 a[4], b[4];
#pragma unroll
    for (int mi = 0; mi < 4; mi++)
      a[mi] = *(const bf16x8*)(arow + (size_t)mi * 16 * 256 + ks * 32);
#pragma unroll
    for (int nj = 0; nj < 4; nj++)
      b[nj] = *(const bf16x8*)(brow + (size_t)nj * 16 * 256 + ks * 32);
#pragma unroll
    for (int mi = 0; mi < 4; mi++)
#pragma unroll
      for (int nj = 0; nj < 4; nj++)
        acc[mi][nj] = MFMA16(a[mi], b[nj], acc[mi][nj]);
  }
#pragma unroll
  for (int mi = 0; mi < 4; mi++) {
    const int rbase = m0 + wr * 64 + mi * 16 + kb * 4;
#pragma unroll
    for (int nj = 0; nj < 4; nj++) {
      const int c = n0 + wc * 64 + nj * 16 + lr;
      const float bb = bias[c];
#pragma unroll
      for (int r = 0; r < 4; r++) {
        const size_t oi = (size_t)(rbase + r) * 256 + c;
        float v = acc[mi][nj][r] + bb;
        if (add) v += bf2f(accb[oi]);
        accb[oi] = f2bf(v);
      }
    }
  }
}

// ---------------- conv1x1: [relu(accb)|xu|res] @ convT^T -> relu -> ytmp ----
__global__ __launch_bounds__(256) void k_gemm_conv(const short* __restrict__ accb,
                                                   const short* __restrict__ xu,
                                                   const float* __restrict__ res,
                                                   const short* __restrict__ Bt,
                                                   float* __restrict__ ytmp) {
  const int tid = threadIdx.x;
  const int lane = tid & 63, wid = tid >> 6;
  const int lr = lane & 15, kb = lane >> 4;
  const int wr = wid >> 1, wc = wid & 1;
  const int m0 = blockIdx.y * 128;
  f32x4 acc[4][4];
#pragma unroll
  for (int i = 0; i < 4; i++)
#pragma unroll
    for (int j = 0; j < 4; j++) acc[i][j] = (f32x4){0.f, 0.f, 0.f, 0.f};
  const short* arow1 = accb + (size_t)(m0 + wr * 64 + lr) * 256 + kb * 8;
  const short* arow2 = xu + (size_t)(m0 + wr * 64 + lr) * 256 + kb * 8;
  const short* brow = Bt + (size_t)(wc * 64 + lr) * 640 + kb * 8;
  // segment 1: relu(accb), k 0:256
#pragma unroll
  for (int ks = 0; ks < 8; ks++) {
    bf16x8 a[4], b[4];
#pragma unroll
    for (int mi = 0; mi < 4; mi++) {
      bf16x8 t = *(const bf16x8*)(arow1 + (size_t)mi * 16 * 256 + ks * 32);
#pragma unroll
      for (int u = 0; u < 8; u++)
        t[u] = ((unsigned short)t[u] & 0x8000u) ? (short)0 : t[u];
      a[mi] = t;
    }
#pragma unroll
    for (int nj = 0; nj < 4; nj++)
      b[nj] = *(const bf16x8*)(brow + (size_t)nj * 16 * 640 + ks * 32);
#pragma unroll
    for (int mi = 0; mi < 4; mi++)
#pragma unroll
      for (int nj = 0; nj < 4; nj++)
        acc[mi][nj] = MFMA16(a[mi], b[nj], acc[mi][nj]);
  }
  // segment 2: xu, k 256:512
#pragma unroll
  for (int ks = 8; ks < 16; ks++) {
    bf16x8 a[4], b[4];
#pragma unroll
    for (int mi = 0; mi < 4; mi++)
      a[mi] = *(const bf16x8*)(arow2 + (size_t)mi * 16 * 256 + (ks - 8) * 32);
#pragma unroll
    for (int nj = 0; nj < 4; nj++)
      b[nj] = *(const bf16x8*)(brow + (size_t)nj * 16 * 640 + ks * 32);
#pragma unroll
    for (int mi = 0; mi < 4; mi++)
#pragma unroll
      for (int nj = 0; nj < 4; nj++)
        acc[mi][nj] = MFMA16(a[mi], b[nj], acc[mi][nj]);
  }
  // segment 3: res (transposed gather), k 512:640
  const int bC = (m0 >> 14) * 128;
  const int hh = (m0 >> 7) & 127;
#pragma unroll
  for (int ks = 16; ks < 20; ks++) {
    const int e0 = (ks - 16) * 32 + kb * 8;
    bf16x8 a[4], b[4];
#pragma unroll
    for (int mi = 0; mi < 4; mi++) {
      const int wl = wr * 64 + mi * 16 + lr;
      const float* rp = res + ((size_t)(bC + e0) * 128 + hh) * 128 + wl;
      bf16x8 t;
#pragma unroll
      for (int u = 0; u < 8; u++) t[u] = f2bf(rp[(size_t)u * 16384]);
      a[mi] = t;
    }
#pragma unroll
    for (int nj = 0; nj < 4; nj++)
      b[nj] = *(const bf16x8*)(brow + (size_t)nj * 16 * 640 + ks * 32);
#pragma unroll
    for (int mi = 0; mi < 4; mi++)
#pragma unroll
      for (int nj = 0; nj < 4; nj++)
        acc[mi][nj] = MFMA16(a[mi], b[nj], acc[mi][nj]);
  }
#pragma unroll
  for (int mi = 0; mi < 4; mi++) {
    const int rbase = m0 + wr * 64 + mi * 16 + kb * 4;
#pragma unroll
    for (int nj = 0; nj < 4; nj++) {
      const int c = wc * 64 + nj * 16 + lr;
#pragma unroll
      for (int r = 0; r < 4; r++)
        ytmp[(size_t)(rbase + r) * 128 + c] = fmaxf(acc[mi][nj][r], 0.f);
    }
  }
}

// ---------------- BN stats pass 1: partial sums per 512-token block --------
__global__ __launch_bounds__(256) void k_bnstats1(const float* __restrict__ y,
                                                  float* __restrict__ partial) {
  const int blk = blockIdx.x, tid = threadIdx.x;
  const int ch = tid & 127, sub = tid >> 7;
  float s = 0.f, s2 = 0.f;
  const float* p = y + (size_t)(blk * 512 + sub) * 128 + ch;
  for (int i = 0; i < 256; i++) {
    float v = p[(size_t)i * 256];
    s += v; s2 += v * v;
  }
  __shared__ float rs[2][128], rs2[2][128];
  rs[sub][ch] = s; rs2[sub][ch] = s2;
  __syncthreads();
  if (tid < 128) {
    partial[(size_t)(blk * 128 + tid) * 2]     = rs[0][tid] + rs[1][tid];
    partial[(size_t)(blk * 128 + tid) * 2 + 1] = rs2[0][tid] + rs2[1][tid];
  }
}

// ---------------- BN stats pass 2 ----------------
__global__ __launch_bounds__(128) void k_bnstats2(const float* __restrict__ partial,
                                                  float* __restrict__ stats) {
  const int ch = threadIdx.x;
  float s = 0.f, s2 = 0.f;
  for (int i = 0; i < 128; i++) {
    s  += partial[(size_t)(i * 128 + ch) * 2];
    s2 += partial[(size_t)(i * 128 + ch) * 2 + 1];
  }
  const float mu = s * (1.f / 65536.f);
  const float var = s2 * (1.f / 65536.f) - mu * mu;   // biased
  stats[ch * 2] = mu;
  stats[ch * 2 + 1] = rsqrtf(var + 1e-5f);
}

// ---------------- BN apply + transpose to (B,E,H,W) ----------------
__global__ __launch_bounds__(256) void k_bnout(const float* __restrict__ y,
                                               const float* __restrict__ stats,
                                               const float* __restrict__ gamma,
                                               const float* __restrict__ beta,
                                               float* __restrict__ out) {
  const int bh = blockIdx.x;
  const int b = bh >> 7, h = bh & 127;
  const int w = threadIdx.x & 127, eh = threadIdx.x >> 7;
  const float* yp = y + (size_t)(bh * 128 + w) * 128;
  for (int e2 = 0; e2 < 64; e2++) {
    const int e = e2 * 2 + eh;
    const float mu = stats[e * 2], rstd = stats[e * 2 + 1];
    const float v = yp[e];
    out[((size_t)(b * 128 + e) << 14) + h * 128 + w] =
        (v - mu) * rstd * gamma[e] + beta[e];
  }
}

// ---------------- launcher ----------------
extern "C" void kernel_launch(void* const* d_in, const int* in_sizes, int n_in,
                              void* d_out, int out_size, void* d_ws, size_t ws_size,
                              hipStream_t stream) {
  const float* x      = (const float*)d_in[0];
  const float* res    = (const float*)d_in[1];
  const float* wq_h   = (const float*)d_in[2];
  const float* wkv_h  = (const float*)d_in[3];
  const float* wo_h   = (const float*)d_in[4];
  const float* wob_h  = (const float*)d_in[5];
  const float* wq_w   = (const float*)d_in[6];
  const float* wkv_w  = (const float*)d_in[7];
  const float* wo_w   = (const float*)d_in[8];
  const float* wob_w  = (const float*)d_in[9];
  const float* conv_w = (const float*)d_in[10];
  const float* gamma  = (const float*)d_in[11];
  const float* beta   = (const float*)d_in[12];

  char* ws = (char*)d_ws;
  short* wqkvT[2] = {(short*)(ws + 0), (short*)(ws + 393216)};
  short* woT[2]   = {(short*)(ws + 786432), (short*)(ws + 917504)};
  short* convT    = (short*)(ws + 1048576);
  short* xu       = (short*)(ws + 1245184);
  short* Qp       = (short*)(ws + 34799616);
  short* Kp       = Qp + 16777216;
  short* Vp       = Kp + 16777216;
  float* ytmp     = (float*)(ws + 34799616);   // aliases Q plane (dead by then)
  float* partial  = (float*)(ws + 68354048);   // aliases K plane
  float* stats    = (float*)(ws + 68485120);
  short* accb     = (short*)d_out;             // axial sum scratch in d_out
  float* out      = (float*)d_out;

  if (ws_size < 135462912ull)
    fprintf(stderr, "kernel_launch: ws_size %zu < 135462912\n", ws_size);

  // weight prep
  k_wt<<<dim3(8, 8),  256, 0, stream>>>(wq_h,  256, 256, wqkvT[0]);
  k_wt<<<dim3(8, 16), 256, 0, stream>>>(wkv_h, 256, 512, wqkvT[0] + 65536);
  k_wt<<<dim3(8, 8),  256, 0, stream>>>(wq_w,  256, 256, wqkvT[1]);
  k_wt<<<dim3(8, 16), 256, 0, stream>>>(wkv_w, 256, 512, wqkvT[1] + 65536);
  k_wt<<<dim3(8, 8),  256, 0, stream>>>(wo_h,  256, 256, woT[0]);
  k_wt<<<dim3(8, 8),  256, 0, stream>>>(wo_w,  256, 256, woT[1]);
  k_wt<<<dim3(20, 4), 256, 0, stream>>>(conv_w, 640, 128, convT);

  k_upsample<<<512, 256, 0, stream>>>(x, xu);

  const float* wob[2] = {wob_h, wob_w};
  for (int dir = 0; dir < 2; dir++) {
    k_gemm_qkv<<<dim3(6, 512), 256, 0, stream>>>(xu, wqkvT[dir], Qp);
    k_attn<<<1024, 256, 0, stream>>>(Qp, Kp, Vp, dir);
    k_gemm_proj<<<dim3(2, 512), 256, 0, stream>>>(Qp, woT[dir], wob[dir], accb, dir);
  }

  k_gemm_conv<<<dim3(1, 512), 256, 0, stream>>>(accb, xu, res, convT, ytmp);
  k_bnstats1<<<128, 256, 0, stream>>>(ytmp, partial);
  k_bnstats2<<<1, 128, 0, stream>>>(partial, stats);
  k_bnout<<<512, 256, 0, stream>>>(ytmp, stats, gamma, beta, out);
}

// Round 3
// 466.340 us; speedup vs baseline: 4.5569x; 1.2607x over previous
//
#include <hip/hip_runtime.h>
#include <hip/hip_bf16.h>
#include <cstdio>

// BlockAxialUp on MI355X, round 3: fix upsample (32-way LDS bank conflict),
// fuse weight-prep launches. GEMM/attn structure unchanged from round 2.
//
// ws layout (bytes):
//   0        wqkvT_h bf16 [768][256]   (rows: q 0:256, k 256:512, v 512:768)
//   393216   wqkvT_w
//   786432   woT_h  bf16 [256][256]
//   917504   woT_w
//   1048576  convT  bf16 [128][640]
//   1245184  xu     bf16 [65536][256]
//   34799616 Q plane bf16 [65536][256]   (O in-place; later ytmp f32 [65536][128])
//   68354048 K plane                     (later partial f32 + stats)
//   101908480 V plane                    -> end 135462912 (~129 MB)
// accb (ah+aw, bf16 [65536][256]) lives in d_out; final f32 output overwrites it.

typedef short bf16x8 __attribute__((ext_vector_type(8)));
typedef float f32x4 __attribute__((ext_vector_type(4)));

#define MFMA16(a, b, c) __builtin_amdgcn_mfma_f32_16x16x32_bf16((a), (b), (c), 0, 0, 0)

__device__ __forceinline__ short f2bf(float v) {
  __hip_bfloat16 h = __float2bfloat16(v);
  union { __hip_bfloat16 h; short s; } u; u.h = h; return u.s;
}
__device__ __forceinline__ float bf2f(short s) {
  return __uint_as_float(((unsigned int)(unsigned short)s) << 16);
}

// ---------------- fused weight prep: dst[n][k] = bf16(src[k][n]) ------------
struct WtAll {
  const float* src[7];
  short* dst[7];
  int K[7], N[7], tile0[7];
};

__global__ __launch_bounds__(256) void k_wt_all(WtAll P) {
  const int bid = blockIdx.x;
  int i = 0;
#pragma unroll
  for (int j = 1; j < 7; j++) if (bid >= P.tile0[j]) i = j;
  const float* src = P.src[i];
  short* dst = P.dst[i];
  const int K = P.K[i], N = P.N[i];
  const int local = bid - P.tile0[i];
  const int ktiles = K >> 5;
  const int nt = local / ktiles, kt = local - nt * ktiles;
  const int k0 = kt * 32, n0 = nt * 32;
  __shared__ float tile[32][33];
  const int tx = threadIdx.x & 31, ty = threadIdx.x >> 5;
#pragma unroll
  for (int r = 0; r < 4; r++)
    tile[ty + r * 8][tx] = src[(size_t)(k0 + ty + r * 8) * N + n0 + tx];
  __syncthreads();
#pragma unroll
  for (int r = 0; r < 4; r++)
    dst[(size_t)(n0 + ty + r * 8) * K + k0 + tx] = f2bf(tile[tx][ty + r * 8]);
}

// ---------------- upsample 2x bilinear align_corners (conflict-free) --------
// block = (b*128 + h_out, channel-quarter z); 64 channels per block.
// vertical interp fused into the coalesced global load; LDS row [c][w] with
// stride 65 (gcd(65,32)=1 -> conflict-free stores); bf16x8 output stores.
__global__ __launch_bounds__(256) void k_upsample(const float* __restrict__ x,
                                                  short* __restrict__ xu) {
  __shared__ float ldsV[64][65];
  const int bh = blockIdx.x, z = blockIdx.y;
  const int b = bh >> 7, h = bh & 127;
  const float chf = h * (63.0f / 127.0f);
  int i0 = (int)chf; if (i0 > 62) i0 = 62;
  const float wh = chf - (float)i0;
  const int t = threadIdx.x;
  const int cbase = z * 64;
  const float* xb = x + ((size_t)(b * 256 + cbase) * 64 + i0) * 64;
#pragma unroll
  for (int p = 0; p < 16; p++) {
    const int li = p * 256 + t;
    const int c = li >> 6, w = li & 63;
    const float* px = xb + (size_t)c * 4096 + w;
    const float v0 = px[0], v1 = px[64];
    ldsV[c][w] = v0 * (1.f - wh) + v1 * wh;
  }
  __syncthreads();
  const int cg = t & 7, wi = t >> 3;
  short* xout = xu + (size_t)(bh * 128) * 256 + cbase + cg * 8;
#pragma unroll
  for (int p = 0; p < 4; p++) {
    const int w = p * 32 + wi;
    const float cwf = w * (63.0f / 127.0f);
    int j0 = (int)cwf; if (j0 > 62) j0 = 62;
    const float ww = cwf - (float)j0;
    bf16x8 o;
#pragma unroll
    for (int u = 0; u < 8; u++) {
      const float v0 = ldsV[cg * 8 + u][j0], v1 = ldsV[cg * 8 + u][j0 + 1];
      o[u] = f2bf(v0 * (1.f - ww) + v1 * ww);
    }
    *(bf16x8*)(xout + (size_t)w * 256) = o;
  }
}

// ---------------- QKV GEMM: [65536,256] @ Bt[768,256]^T -> planes ----------
__global__ __launch_bounds__(256) void k_gemm_qkv(const short* __restrict__ A,
                                                  const short* __restrict__ Bt,
                                                  short* __restrict__ QKV) {
  const int tid = threadIdx.x;
  const int lane = tid & 63, wid = tid >> 6;
  const int lr = lane & 15, kb = lane >> 4;
  const int wr = wid >> 1, wc = wid & 1;
  const int m0 = blockIdx.y * 128, n0 = blockIdx.x * 128;
  f32x4 acc[4][4];
#pragma unroll
  for (int i = 0; i < 4; i++)
#pragma unroll
    for (int j = 0; j < 4; j++) acc[i][j] = (f32x4){0.f, 0.f, 0.f, 0.f};
  const short* arow = A + (size_t)(m0 + wr * 64 + lr) * 256 + kb * 8;
  const short* brow = Bt + (size_t)(n0 + wc * 64 + lr) * 256 + kb * 8;
#pragma unroll
  for (int ks = 0; ks < 8; ks++) {
    bf16x8 a[4], b[4];
#pragma unroll
    for (int mi = 0; mi < 4; mi++)
      a[mi] = *(const bf16x8*)(arow + (size_t)mi * 16 * 256 + ks * 32);
#pragma unroll
    for (int nj = 0; nj < 4; nj++)
      b[nj] = *(const bf16x8*)(brow + (size_t)nj * 16 * 256 + ks * 32);
#pragma unroll
    for (int mi = 0; mi < 4; mi++)
#pragma unroll
      for (int nj = 0; nj < 4; nj++)
        acc[mi][nj] = MFMA16(a[mi], b[nj], acc[mi][nj]);
  }
  short* outp = QKV + (size_t)(n0 >> 8) * 16777216;
  const int colb = (n0 & 255) + wc * 64;
#pragma unroll
  for (int mi = 0; mi < 4; mi++) {
    const int rbase = m0 + wr * 64 + mi * 16 + kb * 4;
#pragma unroll
    for (int nj = 0; nj < 4; nj++) {
      const int c = colb + nj * 16 + lr;
#pragma unroll
      for (int r = 0; r < 4; r++)
        outp[(size_t)(rbase + r) * 256 + c] = f2bf(acc[mi][nj][r]);
    }
  }
}

// ---------------- axial attention (one block = one (seq, head)) ------------
__global__ __launch_bounds__(256) void k_attn(short* __restrict__ Q,
                                              const short* __restrict__ Kp,
                                              const short* __restrict__ Vp,
                                              int dir) {
  __shared__ __align__(16) short Ps[128][136];
  __shared__ __align__(16) short Vt[128][40];
  const int bid = blockIdx.x;
  const int head = bid & 1, s = bid >> 1;
  const int b = s >> 7, pos = s & 127;
  const int tok0 = b * 16384 + (dir ? pos * 128 : pos);
  const int tstep = dir ? 1 : 128;
  const int cb = head * 128;
  const int tid = threadIdx.x;
  const int lane = tid & 63, wid = tid >> 6;
  const int lr = lane & 15, kb = lane >> 4;

  f32x4 acc[2][8];
#pragma unroll
  for (int i = 0; i < 2; i++)
#pragma unroll
    for (int j = 0; j < 8; j++) acc[i][j] = (f32x4){0.f, 0.f, 0.f, 0.f};

  // phase A: S = Q K^T
#pragma unroll
  for (int es = 0; es < 4; es++) {
    const int e0 = es * 32 + kb * 8;
    bf16x8 aq[2], bk[8];
#pragma unroll
    for (int mi = 0; mi < 2; mi++)
      aq[mi] = *(const bf16x8*)(Q + (size_t)(tok0 + (wid * 32 + mi * 16 + lr) * tstep) * 256 + cb + e0);
#pragma unroll
    for (int nj = 0; nj < 8; nj++)
      bk[nj] = *(const bf16x8*)(Kp + (size_t)(tok0 + (nj * 16 + lr) * tstep) * 256 + cb + e0);
#pragma unroll
    for (int mi = 0; mi < 2; mi++)
#pragma unroll
      for (int nj = 0; nj < 8; nj++)
        acc[mi][nj] = MFMA16(aq[mi], bk[nj], acc[mi][nj]);
  }

  // softmax over cols
  const float scale = 0.08838834764831845f;   // 128^-0.5
#pragma unroll
  for (int mi = 0; mi < 2; mi++) {
#pragma unroll
    for (int r = 0; r < 4; r++) {
      float m = acc[mi][0][r];
#pragma unroll
      for (int nj = 1; nj < 8; nj++) m = fmaxf(m, acc[mi][nj][r]);
      m = fmaxf(m, __shfl_xor(m, 1)); m = fmaxf(m, __shfl_xor(m, 2));
      m = fmaxf(m, __shfl_xor(m, 4)); m = fmaxf(m, __shfl_xor(m, 8));
      float p[8], sum = 0.f;
#pragma unroll
      for (int nj = 0; nj < 8; nj++) { p[nj] = __expf((acc[mi][nj][r] - m) * scale); sum += p[nj]; }
      sum += __shfl_xor(sum, 1); sum += __shfl_xor(sum, 2);
      sum += __shfl_xor(sum, 4); sum += __shfl_xor(sum, 8);
      const float inv = 1.f / sum;
      const int prow = wid * 32 + mi * 16 + kb * 4 + r;
#pragma unroll
      for (int nj = 0; nj < 8; nj++) Ps[prow][nj * 16 + lr] = f2bf(p[nj] * inv);
    }
  }

  // phase C: O = P V
#pragma unroll
  for (int i = 0; i < 2; i++)
#pragma unroll
    for (int j = 0; j < 8; j++) acc[i][j] = (f32x4){0.f, 0.f, 0.f, 0.f};

  const int tt2 = tid & 15, eb = (tid >> 4) * 8;
  for (int j0 = 0; j0 < 4; j0++) {
    const int j = j0 * 32;
    const int t0 = j + 2 * tt2;
    bf16x8 v0 = *(const bf16x8*)(Vp + (size_t)(tok0 + t0 * tstep) * 256 + cb + eb);
    bf16x8 v1 = *(const bf16x8*)(Vp + (size_t)(tok0 + (t0 + 1) * tstep) * 256 + cb + eb);
    __syncthreads();
#pragma unroll
    for (int i = 0; i < 8; i++)
      *(unsigned int*)&Vt[eb + i][2 * tt2] =
          (unsigned int)(unsigned short)v0[i] | ((unsigned int)(unsigned short)v1[i] << 16);
    __syncthreads();
    bf16x8 ap[2], bv[8];
#pragma unroll
    for (int mi = 0; mi < 2; mi++)
      ap[mi] = *(const bf16x8*)(&Ps[wid * 32 + mi * 16 + lr][j + kb * 8]);
#pragma unroll
    for (int nj = 0; nj < 8; nj++)
      bv[nj] = *(const bf16x8*)(&Vt[nj * 16 + lr][kb * 8]);
#pragma unroll
    for (int mi = 0; mi < 2; mi++)
#pragma unroll
      for (int nj = 0; nj < 8; nj++)
        acc[mi][nj] = MFMA16(ap[mi], bv[nj], acc[mi][nj]);
  }

  // write O over Q
#pragma unroll
  for (int mi = 0; mi < 2; mi++) {
    const int rbase = wid * 32 + mi * 16 + kb * 4;
#pragma unroll
    for (int nj = 0; nj < 8; nj++) {
      const int c = cb + nj * 16 + lr;
#pragma unroll
      for (int r = 0; r < 4; r++)
        Q[(size_t)(tok0 + (rbase + r) * tstep) * 256 + c] = f2bf(acc[mi][nj][r]);
    }
  }
}

// ---------------- out-proj: accb (+)= O @ woT^T + bias ----------------
__global__ __launch_bounds__(256) void k_gemm_proj(const short* __restrict__ O,
                                                   const short* __restrict__ Bt,
                                                   const float* __restrict__ bias,
                                                   short* __restrict__ accb, int add) {
  const int tid = threadIdx.x;
  const int lane = tid & 63, wid = tid >> 6;
  const int lr = lane & 15, kb = lane >> 4;
  const int wr = wid >> 1, wc = wid & 1;
  const int m0 = blockIdx.y * 128, n0 = blockIdx.x * 128;
  f32x4 acc[4][4];
#pragma unroll
  for (int i = 0; i < 4; i++)
#pragma unroll
    for (int j = 0; j < 4; j++) acc[i][j] = (f32x4){0.f, 0.f, 0.f, 0.f};
  const short* arow = O + (size_t)(m0 + wr * 64 + lr) * 256 + kb * 8;
  const short* brow = Bt + (size_t)(n0 + wc * 64 + lr) * 256 + kb * 8;
#pragma unroll
  for (int ks = 0; ks < 8; ks++) {
    bf16x8 a[4], b[4];
#pragma unroll
    for (int mi = 0; mi < 4; mi++)
      a[mi] = *(const bf16x8*)(arow + (size_t)mi * 16 * 256 + ks * 32);
#pragma unroll
    for (int nj = 0; nj < 4; nj++)
      b[nj] = *(const bf16x8*)(brow + (size_t)nj * 16 * 256 + ks * 32);
#pragma unroll
    for (int mi = 0; mi < 4; mi++)
#pragma unroll
      for (int nj = 0; nj < 4; nj++)
        acc[mi][nj] = MFMA16(a[mi], b[nj], acc[mi][nj]);
  }
#pragma unroll
  for (int mi = 0; mi < 4; mi++) {
    const int rbase = m0 + wr * 64 + mi * 16 + kb * 4;
#pragma unroll
    for (int nj = 0; nj < 4; nj++) {
      const int c = n0 + wc * 64 + nj * 16 + lr;
      const float bb = bias[c];
#pragma unroll
      for (int r = 0; r < 4; r++) {
        const size_t oi = (size_t)(rbase + r) * 256 + c;
        float v = acc[mi][nj][r] + bb;
        if (add) v += bf2f(accb[oi]);
        accb[oi] = f2bf(v);
      }
    }
  }
}

// ---------------- conv1x1: [relu(accb)|xu|res] @ convT^T -> relu -> ytmp ----
__global__ __launch_bounds__(256) void k_gemm_conv(const short* __restrict__ accb,
                                                   const short* __restrict__ xu,
                                                   const float* __restrict__ res,
                                                   const short* __restrict__ Bt,
                                                   float* __restrict__ ytmp) {
  const int tid = threadIdx.x;
  const int lane = tid & 63, wid = tid >> 6;
  const int lr = lane & 15, kb = lane >> 4;
  const int wr = wid >> 1, wc = wid & 1;
  const int m0 = blockIdx.y * 128;
  f32x4 acc[4][4];
#pragma unroll
  for (int i = 0; i < 4; i++)
#pragma unroll
    for (int j = 0; j < 4; j++) acc[i][j] = (f32x4){0.f, 0.f, 0.f, 0.f};
  const short* arow1 = accb + (size_t)(m0 + wr * 64 + lr) * 256 + kb * 8;
  const short* arow2 = xu + (size_t)(m0 + wr * 64 + lr) * 256 + kb * 8;
  const short* brow = Bt + (size_t)(wc * 64 + lr) * 640 + kb * 8;
#pragma unroll
  for (int ks = 0; ks < 8; ks++) {
    bf16x8 a[4], b[4];
#pragma unroll
    for (int mi = 0; mi < 4; mi++) {
      bf16x8 tv = *(const bf16x8*)(arow1 + (size_t)mi * 16 * 256 + ks * 32);
#pragma unroll
      for (int u = 0; u < 8; u++)
        tv[u] = ((unsigned short)tv[u] & 0x8000u) ? (short)0 : tv[u];
      a[mi] = tv;
    }
#pragma unroll
    for (int nj = 0; nj < 4; nj++)
      b[nj] = *(const bf16x8*)(brow + (size_t)nj * 16 * 640 + ks * 32);
#pragma unroll
    for (int mi = 0; mi < 4; mi++)
#pragma unroll
      for (int nj = 0; nj < 4; nj++)
        acc[mi][nj] = MFMA16(a[mi], b[nj], acc[mi][nj]);
  }
#pragma unroll
  for (int ks = 8; ks < 16; ks++) {
    bf16x8 a[4], b[4];
#pragma unroll
    for (int mi = 0; mi < 4; mi++)
      a[mi] = *(const bf16x8*)(arow2 + (size_t)mi * 16 * 256 + (ks - 8) * 32);
#pragma unroll
    for (int nj = 0; nj < 4; nj++)
      b[nj] = *(const bf16x8*)(brow + (size_t)nj * 16 * 640 + ks * 32);
#pragma unroll
    for (int mi = 0; mi < 4; mi++)
#pragma unroll
      for (int nj = 0; nj < 4; nj++)
        acc[mi][nj] = MFMA16(a[mi], b[nj], acc[mi][nj]);
  }
  const int bC = (m0 >> 14) * 128;
  const int hh = (m0 >> 7) & 127;
#pragma unroll
  for (int ks = 16; ks < 20; ks++) {
    const int e0 = (ks - 16) * 32 + kb * 8;
    bf16x8 a[4], b[4];
#pragma unroll
    for (int mi = 0; mi < 4; mi++) {
      const int wl = wr * 64 + mi * 16 + lr;
      const float* rp = res + ((size_t)(bC + e0) * 128 + hh) * 128 + wl;
      bf16x8 tv;
#pragma unroll
      for (int u = 0; u < 8; u++) tv[u] = f2bf(rp[(size_t)u * 16384]);
      a[mi] = tv;
    }
#pragma unroll
    for (int nj = 0; nj < 4; nj++)
      b[nj] = *(const bf16x8*)(brow + (size_t)nj * 16 * 640 + ks * 32);
#pragma unroll
    for (int mi = 0; mi < 4; mi++)
#pragma unroll
      for (int nj = 0; nj < 4; nj++)
        acc[mi][nj] = MFMA16(a[mi], b[nj], acc[mi][nj]);
  }
#pragma unroll
  for (int mi = 0; mi < 4; mi++) {
    const int rbase = m0 + wr * 64 + mi * 16 + kb * 4;
#pragma unroll
    for (int nj = 0; nj < 4; nj++) {
      const int c = wc * 64 + nj * 16 + lr;
#pragma unroll
      for (int r = 0; r < 4; r++)
        ytmp[(size_t)(rbase + r) * 128 + c] = fmaxf(acc[mi][nj][r], 0.f);
    }
  }
}

// ---------------- BN stats pass 1 ----------------
__global__ __launch_bounds__(256) void k_bnstats1(const float* __restrict__ y,
                                                  float* __restrict__ partial) {
  const int blk = blockIdx.x, tid = threadIdx.x;
  const int ch = tid & 127, sub = tid >> 7;
  float s = 0.f, s2 = 0.f;
  const float* p = y + (size_t)(blk * 512 + sub) * 128 + ch;
  for (int i = 0; i < 256; i++) {
    float v = p[(size_t)i * 256];
    s += v; s2 += v * v;
  }
  __shared__ float rs[2][128], rs2[2][128];
  rs[sub][ch] = s; rs2[sub][ch] = s2;
  __syncthreads();
  if (tid < 128) {
    partial[(size_t)(blk * 128 + tid) * 2]     = rs[0][tid] + rs[1][tid];
    partial[(size_t)(blk * 128 + tid) * 2 + 1] = rs2[0][tid] + rs2[1][tid];
  }
}

// ---------------- BN stats pass 2 ----------------
__global__ __launch_bounds__(128) void k_bnstats2(const float* __restrict__ partial,
                                                  float* __restrict__ stats) {
  const int ch = threadIdx.x;
  float s = 0.f, s2 = 0.f;
  for (int i = 0; i < 128; i++) {
    s  += partial[(size_t)(i * 128 + ch) * 2];
    s2 += partial[(size_t)(i * 128 + ch) * 2 + 1];
  }
  const float mu = s * (1.f / 65536.f);
  const float var = s2 * (1.f / 65536.f) - mu * mu;
  stats[ch * 2] = mu;
  stats[ch * 2 + 1] = rsqrtf(var + 1e-5f);
}

// ---------------- BN apply + transpose to (B,E,H,W) ----------------
__global__ __launch_bounds__(256) void k_bnout(const float* __restrict__ y,
                                               const float* __restrict__ stats,
                                               const float* __restrict__ gamma,
                                               const float* __restrict__ beta,
                                               float* __restrict__ out) {
  const int bh = blockIdx.x;
  const int b = bh >> 7, h = bh & 127;
  const int w = threadIdx.x & 127, eh = threadIdx.x >> 7;
  const float* yp = y + (size_t)(bh * 128 + w) * 128;
  for (int e2 = 0; e2 < 64; e2++) {
    const int e = e2 * 2 + eh;
    const float mu = stats[e * 2], rstd = stats[e * 2 + 1];
    const float v = yp[e];
    out[((size_t)(b * 128 + e) << 14) + h * 128 + w] =
        (v - mu) * rstd * gamma[e] + beta[e];
  }
}

// ---------------- launcher ----------------
extern "C" void kernel_launch(void* const* d_in, const int* in_sizes, int n_in,
                              void* d_out, int out_size, void* d_ws, size_t ws_size,
                              hipStream_t stream) {
  const float* x      = (const float*)d_in[0];
  const float* res    = (const float*)d_in[1];
  const float* wq_h   = (const float*)d_in[2];
  const float* wkv_h  = (const float*)d_in[3];
  const float* wo_h   = (const float*)d_in[4];
  const float* wob_h  = (const float*)d_in[5];
  const float* wq_w   = (const float*)d_in[6];
  const float* wkv_w  = (const float*)d_in[7];
  const float* wo_w   = (const float*)d_in[8];
  const float* wob_w  = (const float*)d_in[9];
  const float* conv_w = (const float*)d_in[10];
  const float* gamma  = (const float*)d_in[11];
  const float* beta   = (const float*)d_in[12];

  char* ws = (char*)d_ws;
  short* wqkvT[2] = {(short*)(ws + 0), (short*)(ws + 393216)};
  short* woT[2]   = {(short*)(ws + 786432), (short*)(ws + 917504)};
  short* convT    = (short*)(ws + 1048576);
  short* xu       = (short*)(ws + 1245184);
  short* Qp       = (short*)(ws + 34799616);
  short* Kp       = Qp + 16777216;
  short* Vp       = Kp + 16777216;
  float* ytmp     = (float*)(ws + 34799616);   // aliases Q plane (dead by then)
  float* partial  = (float*)(ws + 68354048);   // aliases K plane
  float* stats    = (float*)(ws + 68485120);
  short* accb     = (short*)d_out;             // axial sum scratch in d_out
  float* out      = (float*)d_out;

  if (ws_size < 135462912ull)
    fprintf(stderr, "kernel_launch: ws_size %zu < 135462912\n", ws_size);

  // fused weight prep: starts 0,64,192,256,384,448,512; total 592 tiles
  WtAll P;
  P.src[0] = wq_h;  P.dst[0] = wqkvT[0];          P.K[0] = 256; P.N[0] = 256; P.tile0[0] = 0;
  P.src[1] = wkv_h; P.dst[1] = wqkvT[0] + 65536;  P.K[1] = 256; P.N[1] = 512; P.tile0[1] = 64;
  P.src[2] = wq_w;  P.dst[2] = wqkvT[1];          P.K[2] = 256; P.N[2] = 256; P.tile0[2] = 192;
  P.src[3] = wkv_w; P.dst[3] = wqkvT[1] + 65536;  P.K[3] = 256; P.N[3] = 512; P.tile0[3] = 256;
  P.src[4] = wo_h;  P.dst[4] = woT[0];            P.K[4] = 256; P.N[4] = 256; P.tile0[4] = 384;
  P.src[5] = wo_w;  P.dst[5] = woT[1];            P.K[5] = 256; P.N[5] = 256; P.tile0[5] = 448;
  P.src[6] = conv_w;P.dst[6] = convT;             P.K[6] = 640; P.N[6] = 128; P.tile0[6] = 512;
  k_wt_all<<<592, 256, 0, stream>>>(P);

  k_upsample<<<dim3(512, 4), 256, 0, stream>>>(x, xu);

  const float* wob[2] = {wob_h, wob_w};
  for (int dir = 0; dir < 2; dir++) {
    k_gemm_qkv<<<dim3(6, 512), 256, 0, stream>>>(xu, wqkvT[dir], Qp);
    k_attn<<<1024, 256, 0, stream>>>(Qp, Kp, Vp, dir);
    k_gemm_proj<<<dim3(2, 512), 256, 0, stream>>>(Qp, woT[dir], wob[dir], accb, dir);
  }

  k_gemm_conv<<<dim3(1, 512), 256, 0, stream>>>(accb, xu, res, convT, ytmp);
  k_bnstats1<<<128, 256, 0, stream>>>(ytmp, partial);
  k_bnstats2<<<1, 128, 0, stream>>>(partial, stats);
  k_bnout<<<512, 256, 0, stream>>>(ytmp, stats, gamma, beta, out);
}